// Round 5
// baseline (145.558 us; speedup 1.0000x reference)
//
#include <hip/hip_runtime.h>

// B=8, N=1024, C=768, H=12, D=64.
// Pipeline: [convert x -> bf16] [transpose+convert Wqkv, Wproj -> Bt bf16]
//           [gemm_qkv: q(scaled),k in [B,H,N,D]; v transposed [B,H,D,N]]
//           [attn: exp-softmax (no max sub), K/Vt double-buffered LDS (R3)]
//           [gemm_proj -> f32 out + bias]
// R5: GEMM main loop -> counted vmcnt(8) (T4), raw s_barrier pairs, 2 tiles
//     in flight; vmcnt(0) only on the final tile. Swizzle kept (conflicts=0).

typedef short  bf16x8_t __attribute__((ext_vector_type(8)));
typedef float  f32x4_t  __attribute__((ext_vector_type(4)));

static __device__ __forceinline__ unsigned short f2bf(float f) {
    union { float f; unsigned u; } v; v.f = f;
    unsigned r = v.u + 0x7fffu + ((v.u >> 16) & 1u);   // RNE
    return (unsigned short)(r >> 16);
}

typedef __attribute__((address_space(1))) const unsigned gas_u32;
typedef __attribute__((address_space(3))) unsigned las_u32;
static __device__ __forceinline__ void gload16(const void* g, void* l) {
    __builtin_amdgcn_global_load_lds((gas_u32*)g, (las_u32*)l, 16, 0, 0);
}

// Stage one 128x64 bf16 tile (16KB): 4 gload_lds_dwordx4 per thread, linear
// LDS dest, chunk-XOR swizzle applied on the GLOBAL source (G21 both-sides).
#define STAGE_T(DST, SRC, K0)                                              \
    _Pragma("unroll")                                                      \
    for (int p_ = 0; p_ < 4; ++p_) {                                       \
        const int base_ = p_*256 + w64;                                    \
        const int i_ = base_ + lane;                                       \
        const int row_ = i_ >> 3;                                          \
        const int cb_ = ((i_ & 7) ^ (row_ & 7)) * 8;                       \
        gload16((SRC) + (size_t)row_*768 + (K0) + cb_, &(DST)[base_*8]);   \
    }

// One BK=64 K-tile of MFMA from swizzled LDS tiles (read XOR undoes store XOR).
#define COMPUTE_T(AS, BS)                                                  \
    {                                                                      \
        bf16x8_t a_[2][4], b_[2][4];                                       \
        _Pragma("unroll")                                                  \
        for (int ks_ = 0; ks_ < 2; ++ks_) {                                \
            _Pragma("unroll")                                              \
            for (int m_ = 0; m_ < 4; ++m_) {                               \
                const int ra_ = wm*64 + m_*16 + l15;                       \
                a_[ks_][m_] = *(const bf16x8_t*)&(AS)[ra_*64 + ((ks_*4 + lhi) ^ (ra_ & 7))*8]; \
                const int rb_ = wn*64 + m_*16 + l15;                       \
                b_[ks_][m_] = *(const bf16x8_t*)&(BS)[rb_*64 + ((ks_*4 + lhi) ^ (rb_ & 7))*8]; \
            }                                                              \
        }                                                                  \
        _Pragma("unroll")                                                  \
        for (int m_ = 0; m_ < 4; ++m_)                                     \
            _Pragma("unroll")                                              \
            for (int n_ = 0; n_ < 4; ++n_) {                               \
                acc[m_][n_] = __builtin_amdgcn_mfma_f32_16x16x32_bf16(a_[0][m_], b_[0][n_], acc[m_][n_], 0, 0, 0); \
                acc[m_][n_] = __builtin_amdgcn_mfma_f32_16x16x32_bf16(a_[1][m_], b_[1][n_], acc[m_][n_], 0, 0, 0); \
            }                                                              \
    }

#define WAIT8 asm volatile("s_waitcnt vmcnt(8)" ::: "memory")
#define WAIT0 asm volatile("s_waitcnt vmcnt(0)" ::: "memory")
#define BAR   __builtin_amdgcn_s_barrier()

// Counted-vmcnt double-buffered main loop over 12 half-tiles (K=768, BK=64).
#define GEMM_MAIN_LOOP(Ab, Bb)                                             \
    STAGE_T(As0, Ab, 0)                                                    \
    STAGE_T(Bs0, Bb, 0)                                                    \
    STAGE_T(As1, Ab, 64)                                                   \
    STAGE_T(Bs1, Bb, 64)                                                   \
    _Pragma("unroll 1")                                                    \
    for (int t = 0; t < 6; ++t) {                                          \
        WAIT8; BAR;                                                        \
        COMPUTE_T(As0, Bs0)                                                \
        BAR;                                                               \
        if (t < 5) {                                                       \
            STAGE_T(As0, Ab, t*128 + 128)                                  \
            STAGE_T(Bs0, Bb, t*128 + 128)                                  \
            WAIT8;                                                         \
        } else {                                                           \
            WAIT0;                                                         \
        }                                                                  \
        BAR;                                                               \
        COMPUTE_T(As1, Bs1)                                                \
        BAR;                                                               \
        if (t < 5) {                                                       \
            STAGE_T(As1, Ab, t*128 + 192)                                  \
            STAGE_T(Bs1, Bb, t*128 + 192)                                  \
        }                                                                  \
    }

// ---------------- pre-pass: x f32 -> bf16 (same layout)
__global__ __launch_bounds__(256) void convert_x(
    const float* __restrict__ src, unsigned short* __restrict__ dst)
{
    const int i = blockIdx.x * 256 + threadIdx.x;
    const float4 v = ((const float4*)src)[i];
    ushort4 o; o.x = f2bf(v.x); o.y = f2bf(v.y); o.z = f2bf(v.z); o.w = f2bf(v.w);
    ((ushort4*)dst)[i] = o;
}

// ---------------- pre-pass: W [R][C] f32 -> Wt [C][R] bf16
__global__ __launch_bounds__(256) void transpose_cvt(
    const float* __restrict__ src, unsigned short* __restrict__ dst, int R, int C)
{
    __shared__ unsigned short tile[32][33];
    const int tx = threadIdx.x & 31, ty = threadIdx.x >> 5;
    const int bx = blockIdx.x, by = blockIdx.y;
    #pragma unroll
    for (int j = 0; j < 32; j += 8)
        tile[ty + j][tx] = f2bf(src[(size_t)(by*32 + ty + j) * C + bx*32 + tx]);
    __syncthreads();
    #pragma unroll
    for (int j = 0; j < 32; j += 8)
        dst[(size_t)(bx*32 + ty + j) * R + by*32 + tx] = tile[tx][ty + j];
}

// ---------------- GEMM1: [8192x768]bf16 @ Wt[2304x768]bf16 -> q,k,vT scatter
__global__ __launch_bounds__(256) void gemm_qkv_bf16(
    const unsigned short* __restrict__ A, const unsigned short* __restrict__ Bt,
    const float* __restrict__ bias,
    unsigned short* __restrict__ q, unsigned short* __restrict__ kO,
    unsigned short* __restrict__ vT)
{
    __shared__ unsigned short As0[128*64], As1[128*64];   // 16KB each
    __shared__ unsigned short Bs0[128*64], Bs1[128*64];   // total 64KB
    const int tid = threadIdx.x;
    const int id = blockIdx.x;                 // 1152 blocks, 1152%8==0
    const int swz = (id & 7) * 144 + (id >> 3);
    const int n0 = (swz % 18) * 128, m0 = (swz / 18) * 128;

    const int lane = tid & 63, w = tid >> 6;
    const int l15 = lane & 15, lhi = lane >> 4;
    const int wm = w >> 1, wn = w & 1;
    const int w64 = tid & 192;

    const unsigned short* Ab = A  + (size_t)m0 * 768;
    const unsigned short* Bb = Bt + (size_t)n0 * 768;

    f32x4_t acc[4][4] = {};

    GEMM_MAIN_LOOP(Ab, Bb)

    #pragma unroll
    for (int n = 0; n < 4; ++n) {
        const int gcol = n0 + wn*64 + n*16 + l15;         // 0..2303
        const int kk = gcol / 768;                        // 0=q,1=k,2=v
        const int r  = gcol - kk*768;
        const int h  = r >> 6, d = r & 63;
        const float bv = bias[gcol];
        const float sc = (kk == 0) ? 0.125f : 1.0f;
        #pragma unroll
        for (int m = 0; m < 4; ++m) {
            const int grow_base = m0 + wm*64 + m*16 + lhi*4;
            #pragma unroll
            for (int reg = 0; reg < 4; ++reg) {
                const int grow = grow_base + reg;         // b*1024+seq
                const int bb = grow >> 10, seq = grow & 1023;
                const unsigned short ov = f2bf((acc[m][n][reg] + bv) * sc);
                const size_t bh = (size_t)bb*12 + h;
                if (kk == 0)      q [ (bh*1024 + seq)*64 + d ] = ov;
                else if (kk == 1) kO[ (bh*1024 + seq)*64 + d ] = ov;
                else              vT[ (bh*64 + d)*1024 + seq ] = ov;
            }
        }
    }
}

// ---------------- Attention (unchanged from R3): flash w/o max-sub, dbuf K/Vt
__global__ __launch_bounds__(256) void attn2(
    const unsigned short* __restrict__ q, const unsigned short* __restrict__ k,
    const unsigned short* __restrict__ vT, unsigned short* __restrict__ obuf)
{
    __shared__ unsigned short Ks[2][64 * 72];
    __shared__ unsigned short Vs[2][64 * 72];
    __shared__ unsigned short P[4][16 * 72];
    const int tid = threadIdx.x;
    const int id = blockIdx.x;                 // 1536 blocks
    const int swz = (id & 7) * 192 + (id >> 3);
    const int qt = swz & 15, bh = swz >> 4;

    const int lane = tid & 63, w = tid >> 6;
    const int l15 = lane & 15, lhi = lane >> 4;
    const unsigned short* qp = q  + (size_t)bh * 65536;
    const unsigned short* kp = k  + (size_t)bh * 65536;
    const unsigned short* vp = vT + (size_t)bh * 65536;  // [64 d][1024 n]

    bf16x8_t qf[2];
    const int qrow = qt*64 + w*16 + l15;
    #pragma unroll
    for (int ks = 0; ks < 2; ++ks)
        qf[ks] = *(const bf16x8_t*)(qp + (size_t)qrow*64 + ks*32 + lhi*8);

    f32x4_t acco[4] = {};
    float lsum[4] = {0.f, 0.f, 0.f, 0.f};
    unsigned short* Pw = P[w];

    bf16x8_t kr[2], vr[2];
    #pragma unroll
    for (int p = 0; p < 2; ++p) {
        const int idx = p*256 + tid;
        const int rr = idx >> 3, cb = (idx & 7) * 8;
        kr[p] = *(const bf16x8_t*)(kp + (size_t)rr*64 + cb);
        vr[p] = *(const bf16x8_t*)(vp + (size_t)rr*1024 + cb);
    }
    #pragma unroll
    for (int p = 0; p < 2; ++p) {
        const int idx = p*256 + tid;
        const int rr = idx >> 3, cb = (idx & 7) * 8;
        *(bf16x8_t*)&Ks[0][rr*72 + cb] = kr[p];
        *(bf16x8_t*)&Vs[0][rr*72 + cb] = vr[p];
    }

    for (int kt = 0; kt < 16; ++kt) {
        const int cur = kt & 1;
        __syncthreads();
        if (kt < 15) {
            #pragma unroll
            for (int p = 0; p < 2; ++p) {
                const int idx = p*256 + tid;
                const int rr = idx >> 3, cb = (idx & 7) * 8;
                kr[p] = *(const bf16x8_t*)(kp + (size_t)((kt+1)*64 + rr)*64 + cb);
                vr[p] = *(const bf16x8_t*)(vp + (size_t)rr*1024 + (kt+1)*64 + cb);
            }
        }

        f32x4_t accs[4] = {};
        __builtin_amdgcn_s_setprio(1);
        #pragma unroll
        for (int c = 0; c < 4; ++c)
            #pragma unroll
            for (int ks = 0; ks < 2; ++ks) {
                bf16x8_t kf = *(const bf16x8_t*)&Ks[cur][(c*16 + l15)*72 + ks*32 + lhi*8];
                accs[c] = __builtin_amdgcn_mfma_f32_16x16x32_bf16(qf[ks], kf, accs[c], 0, 0, 0);
            }
        __builtin_amdgcn_s_setprio(0);

        #pragma unroll
        for (int c = 0; c < 4; ++c)
            #pragma unroll
            for (int r = 0; r < 4; ++r) {
                const float pv = __expf(accs[c][r]);
                lsum[r] += pv;
                Pw[(lhi*4 + r)*72 + c*16 + l15] = f2bf(pv);
            }

        bf16x8_t pf[2];
        #pragma unroll
        for (int ks = 0; ks < 2; ++ks)
            pf[ks] = *(const bf16x8_t*)&Pw[l15*72 + ks*32 + lhi*8];
        __builtin_amdgcn_s_setprio(1);
        #pragma unroll
        for (int n = 0; n < 4; ++n)
            #pragma unroll
            for (int ks = 0; ks < 2; ++ks) {
                bf16x8_t vf = *(const bf16x8_t*)&Vs[cur][(n*16 + l15)*72 + ks*32 + lhi*8];
                acco[n] = __builtin_amdgcn_mfma_f32_16x16x32_bf16(pf[ks], vf, acco[n], 0, 0, 0);
            }
        __builtin_amdgcn_s_setprio(0);

        if (kt < 15) {
            #pragma unroll
            for (int p = 0; p < 2; ++p) {
                const int idx = p*256 + tid;
                const int rr = idx >> 3, cb = (idx & 7) * 8;
                *(bf16x8_t*)&Ks[cur^1][rr*72 + cb] = kr[p];
                *(bf16x8_t*)&Vs[cur^1][rr*72 + cb] = vr[p];
            }
        }
    }

    #pragma unroll
    for (int r = 0; r < 4; ++r)
        #pragma unroll
        for (int off = 1; off <= 8; off <<= 1)
            lsum[r] += __shfl_xor(lsum[r], off, 64);

    const int b = bh / 12, h = bh % 12;
    #pragma unroll
    for (int n = 0; n < 4; ++n)
        #pragma unroll
        for (int r = 0; r < 4; ++r) {
            const int seq = qt*64 + w*16 + lhi*4 + r;
            obuf[((size_t)(b*1024 + seq))*768 + h*64 + n*16 + l15] = f2bf(acco[n][r] / lsum[r]);
        }
}

// ---------------- GEMM2: obuf[8192x768]bf16 @ Wpt[768x768]bf16 + bias -> f32
__global__ __launch_bounds__(256) void gemm_proj_bf16(
    const unsigned short* __restrict__ A, const unsigned short* __restrict__ Bt,
    const float* __restrict__ bias, float* __restrict__ out)
{
    __shared__ unsigned short As0[128*64], As1[128*64];
    __shared__ unsigned short Bs0[128*64], Bs1[128*64];
    const int tid = threadIdx.x;
    const int id = blockIdx.x;                 // 384 blocks
    const int swz = (id & 7) * 48 + (id >> 3);
    const int n0 = (swz % 6) * 128, m0 = (swz / 6) * 128;

    const int lane = tid & 63, w = tid >> 6;
    const int l15 = lane & 15, lhi = lane >> 4;
    const int wm = w >> 1, wn = w & 1;
    const int w64 = tid & 192;

    const unsigned short* Ab = A  + (size_t)m0 * 768;
    const unsigned short* Bb = Bt + (size_t)n0 * 768;

    f32x4_t acc[4][4] = {};

    GEMM_MAIN_LOOP(Ab, Bb)

    #pragma unroll
    for (int n = 0; n < 4; ++n) {
        const int gcol = n0 + wn*64 + n*16 + l15;
        const float bv = bias[gcol];
        #pragma unroll
        for (int m = 0; m < 4; ++m) {
            const int grow_base = m0 + wm*64 + m*16 + lhi*4;
            #pragma unroll
            for (int reg = 0; reg < 4; ++reg)
                out[(size_t)(grow_base + reg)*768 + gcol] = acc[m][n][reg] + bv;
        }
    }
}

extern "C" void kernel_launch(void* const* d_in, const int* in_sizes, int n_in,
                              void* d_out, int out_size, void* d_ws, size_t ws_size,
                              hipStream_t stream) {
    const float* x     = (const float*)d_in[0];
    const float* Wqkv  = (const float*)d_in[1];
    const float* bqkv  = (const float*)d_in[2];
    const float* Wproj = (const float*)d_in[3];
    const float* bproj = (const float*)d_in[4];
    float* out = (float*)d_out;
    unsigned short* ws = (unsigned short*)d_ws;

    unsigned short* xb    = ws;                       // 6291456
    unsigned short* obuf  = ws;                       // alias (xb dead after gemm_qkv)
    unsigned short* wqt   = ws + 6291456u;            // 1769472
    unsigned short* wpt   = ws + 8060928u;            // 589824
    unsigned short* qb    = ws + 8650752u;            // 6291456
    unsigned short* kb    = ws + 14942208u;           // 6291456
    unsigned short* vTb   = ws + 21233664u;           // 6291456

    convert_x     <<<6144, 256, 0, stream>>>(x, xb);
    transpose_cvt <<<dim3(72, 24), 256, 0, stream>>>(Wqkv, wqt, 768, 2304);
    transpose_cvt <<<dim3(24, 24), 256, 0, stream>>>(Wproj, wpt, 768, 768);
    gemm_qkv_bf16 <<<1152, 256, 0, stream>>>(xb, wqt, bqkv, qb, kb, vTb);
    attn2         <<<1536, 256, 0, stream>>>(qb, kb, vTb, obuf);
    gemm_proj_bf16<<<384,  256, 0, stream>>>(obuf, wpt, bproj, out);
}

// Round 6
// 136.759 us; speedup vs baseline: 1.0643x; 1.0643x over previous
//
#include <hip/hip_runtime.h>

// B=8, N=1024, C=768, H=12, D=64.
// Pipeline: [convert x -> bf16] [transpose+convert Wqkv, Wproj -> Bt bf16]
//           [gemm_qkv 256x128/8w: q(scaled),k in [B,H,N,D]; v transposed]
//           [attn: exp-softmax, single-buffer K/Vt + reg-staged prefetch]
//           [gemm_proj 64x128/4w -> f32 out + bias]
// R6: occupancy + amortization. qkv: 256x128 tile (576 blocks, 16 waves/CU,
//     single 48KB buffer). proj: 64x128 (768 blocks = 3/CU exact). attn:
//     single 27KB buffer -> 5 blocks/CU, T14 reg prefetch kept.

typedef short  bf16x8_t __attribute__((ext_vector_type(8)));
typedef float  f32x4_t  __attribute__((ext_vector_type(4)));

static __device__ __forceinline__ unsigned short f2bf(float f) {
    union { float f; unsigned u; } v; v.f = f;
    unsigned r = v.u + 0x7fffu + ((v.u >> 16) & 1u);   // RNE
    return (unsigned short)(r >> 16);
}

typedef __attribute__((address_space(1))) const unsigned gas_u32;
typedef __attribute__((address_space(3))) unsigned las_u32;
static __device__ __forceinline__ void gload16(const void* g, void* l) {
    __builtin_amdgcn_global_load_lds((gas_u32*)g, (las_u32*)l, 16, 0, 0);
}

#define WAIT0 asm volatile("s_waitcnt vmcnt(0)" ::: "memory")
#define BAR   __builtin_amdgcn_s_barrier()

// Stage a [ROWS x 64] bf16 tile from row-major src (stride 768 u16) into
// linear LDS via gload_lds, chunk-XOR swizzle applied on the GLOBAL source.
// NP = ROWS*8 / NT chunk-passes; NT = threads/block; wb = wave base in block.
#define STAGE_TILE(DST, SRC, K0, NP, NT)                                   \
    _Pragma("unroll")                                                      \
    for (int p_ = 0; p_ < NP; ++p_) {                                      \
        const int base_ = p_*NT + wb;                                      \
        const int i_ = base_ + lane;                                       \
        const int row_ = i_ >> 3;                                          \
        const int cb_ = ((i_ & 7) ^ (row_ & 7)) * 8;                       \
        gload16((SRC) + (size_t)row_*768 + (K0) + cb_, &(DST)[base_*8]);   \
    }

// 4(m) x 4(n) frag compute over BK=64, wave rows wm*64, cols wn*64.
#define COMPUTE_T(AS, BS)                                                  \
    {                                                                      \
        bf16x8_t a_[2][4], b_[2][4];                                       \
        _Pragma("unroll")                                                  \
        for (int ks_ = 0; ks_ < 2; ++ks_) {                                \
            _Pragma("unroll")                                              \
            for (int m_ = 0; m_ < 4; ++m_) {                               \
                const int ra_ = wm*64 + m_*16 + l15;                       \
                a_[ks_][m_] = *(const bf16x8_t*)&(AS)[ra_*64 + ((ks_*4 + lhi) ^ (ra_ & 7))*8]; \
                const int rb_ = wn*64 + m_*16 + l15;                       \
                b_[ks_][m_] = *(const bf16x8_t*)&(BS)[rb_*64 + ((ks_*4 + lhi) ^ (rb_ & 7))*8]; \
            }                                                              \
        }                                                                  \
        _Pragma("unroll")                                                  \
        for (int m_ = 0; m_ < 4; ++m_)                                     \
            _Pragma("unroll")                                              \
            for (int n_ = 0; n_ < 4; ++n_) {                               \
                acc[m_][n_] = __builtin_amdgcn_mfma_f32_16x16x32_bf16(a_[0][m_], b_[0][n_], acc[m_][n_], 0, 0, 0); \
                acc[m_][n_] = __builtin_amdgcn_mfma_f32_16x16x32_bf16(a_[1][m_], b_[1][n_], acc[m_][n_], 0, 0, 0); \
            }                                                              \
    }

// 2(m) x 4(n) frag compute, wave rows wm*32, cols wn*64 (proj 64x128 tile).
#define COMPUTE_P(AS, BS)                                                  \
    {                                                                      \
        bf16x8_t a_[2][2], b_[2][4];                                       \
        _Pragma("unroll")                                                  \
        for (int ks_ = 0; ks_ < 2; ++ks_) {                                \
            _Pragma("unroll")                                              \
            for (int m_ = 0; m_ < 2; ++m_) {                               \
                const int ra_ = wm*32 + m_*16 + l15;                       \
                a_[ks_][m_] = *(const bf16x8_t*)&(AS)[ra_*64 + ((ks_*4 + lhi) ^ (ra_ & 7))*8]; \
            }                                                              \
            _Pragma("unroll")                                              \
            for (int n_ = 0; n_ < 4; ++n_) {                               \
                const int rb_ = wn*64 + n_*16 + l15;                       \
                b_[ks_][n_] = *(const bf16x8_t*)&(BS)[rb_*64 + ((ks_*4 + lhi) ^ (rb_ & 7))*8]; \
            }                                                              \
        }                                                                  \
        _Pragma("unroll")                                                  \
        for (int m_ = 0; m_ < 2; ++m_)                                     \
            _Pragma("unroll")                                              \
            for (int n_ = 0; n_ < 4; ++n_) {                               \
                acc[m_][n_] = __builtin_amdgcn_mfma_f32_16x16x32_bf16(a_[0][m_], b_[0][n_], acc[m_][n_], 0, 0, 0); \
                acc[m_][n_] = __builtin_amdgcn_mfma_f32_16x16x32_bf16(a_[1][m_], b_[1][n_], acc[m_][n_], 0, 0, 0); \
            }                                                              \
    }

// ---------------- pre-pass: x f32 -> bf16 (same layout)
__global__ __launch_bounds__(256) void convert_x(
    const float* __restrict__ src, unsigned short* __restrict__ dst)
{
    const int i = blockIdx.x * 256 + threadIdx.x;
    const float4 v = ((const float4*)src)[i];
    ushort4 o; o.x = f2bf(v.x); o.y = f2bf(v.y); o.z = f2bf(v.z); o.w = f2bf(v.w);
    ((ushort4*)dst)[i] = o;
}

// ---------------- pre-pass: W [R][C] f32 -> Wt [C][R] bf16
__global__ __launch_bounds__(256) void transpose_cvt(
    const float* __restrict__ src, unsigned short* __restrict__ dst, int R, int C)
{
    __shared__ unsigned short tile[32][33];
    const int tx = threadIdx.x & 31, ty = threadIdx.x >> 5;
    const int bx = blockIdx.x, by = blockIdx.y;
    #pragma unroll
    for (int j = 0; j < 32; j += 8)
        tile[ty + j][tx] = f2bf(src[(size_t)(by*32 + ty + j) * C + bx*32 + tx]);
    __syncthreads();
    #pragma unroll
    for (int j = 0; j < 32; j += 8)
        dst[(size_t)(bx*32 + ty + j) * R + by*32 + tx] = tile[tx][ty + j];
}

// ---------------- GEMM1: 256x128 tile, 8 waves, single 48KB buffer
__global__ __launch_bounds__(512, 4) void gemm_qkv_bf16(
    const unsigned short* __restrict__ A, const unsigned short* __restrict__ Bt,
    const float* __restrict__ bias,
    unsigned short* __restrict__ q, unsigned short* __restrict__ kO,
    unsigned short* __restrict__ vT)
{
    __shared__ unsigned short As[256*64];   // 32KB
    __shared__ unsigned short Bs[128*64];   // 16KB
    const int tid = threadIdx.x;
    const int id = blockIdx.x;              // 576 blocks, 576%8==0
    const int swz = (id & 7) * 72 + (id >> 3);
    const int n0 = (swz % 18) * 128, m0 = (swz / 18) * 256;

    const int lane = tid & 63, w = tid >> 6;
    const int l15 = lane & 15, lhi = lane >> 4;
    const int wm = w >> 1, wn = w & 1;      // 4x2 wave grid
    const int wb = tid & 448;               // wave base (512-thread block)

    const unsigned short* Ab = A  + (size_t)m0 * 768;
    const unsigned short* Bb = Bt + (size_t)n0 * 768;

    f32x4_t acc[4][4] = {};

    #pragma unroll 1
    for (int t = 0; t < 12; ++t) {
        STAGE_TILE(As, Ab, t*64, 4, 512)
        STAGE_TILE(Bs, Bb, t*64, 2, 512)
        WAIT0; BAR;
        COMPUTE_T(As, Bs)
        BAR;
    }

    #pragma unroll
    for (int n = 0; n < 4; ++n) {
        const int gcol = n0 + wn*64 + n*16 + l15;         // 0..2303
        const int kk = gcol / 768;                        // 0=q,1=k,2=v
        const int r  = gcol - kk*768;
        const int h  = r >> 6, d = r & 63;
        const float bv = bias[gcol];
        const float sc = (kk == 0) ? 0.125f : 1.0f;
        #pragma unroll
        for (int m = 0; m < 4; ++m) {
            const int grow_base = m0 + wm*64 + m*16 + lhi*4;
            #pragma unroll
            for (int reg = 0; reg < 4; ++reg) {
                const int grow = grow_base + reg;         // b*1024+seq
                const int bb = grow >> 10, seq = grow & 1023;
                const unsigned short ov = f2bf((acc[m][n][reg] + bv) * sc);
                const size_t bh = (size_t)bb*12 + h;
                if (kk == 0)      q [ (bh*1024 + seq)*64 + d ] = ov;
                else if (kk == 1) kO[ (bh*1024 + seq)*64 + d ] = ov;
                else              vT[ (bh*64 + d)*1024 + seq ] = ov;
            }
        }
    }
}

// ---------------- Attention: single-buffer K/Vt + T14 reg-staged prefetch
__global__ __launch_bounds__(256, 5) void attn2(
    const unsigned short* __restrict__ q, const unsigned short* __restrict__ k,
    const unsigned short* __restrict__ vT, unsigned short* __restrict__ obuf)
{
    __shared__ unsigned short Ks[64 * 72];
    __shared__ unsigned short Vs[64 * 72];
    __shared__ unsigned short P[4][16 * 72];   // 27648 B total -> 5 blocks/CU
    const int tid = threadIdx.x;
    const int id = blockIdx.x;                 // 1536 blocks
    const int swz = (id & 7) * 192 + (id >> 3);
    const int qt = swz & 15, bh = swz >> 4;

    const int lane = tid & 63, w = tid >> 6;
    const int l15 = lane & 15, lhi = lane >> 4;
    const unsigned short* qp = q  + (size_t)bh * 65536;
    const unsigned short* kp = k  + (size_t)bh * 65536;
    const unsigned short* vp = vT + (size_t)bh * 65536;  // [64 d][1024 n]

    bf16x8_t qf[2];
    const int qrow = qt*64 + w*16 + l15;
    #pragma unroll
    for (int ks = 0; ks < 2; ++ks)
        qf[ks] = *(const bf16x8_t*)(qp + (size_t)qrow*64 + ks*32 + lhi*8);

    f32x4_t acco[4] = {};
    float lsum[4] = {0.f, 0.f, 0.f, 0.f};
    unsigned short* Pw = P[w];

    const int rr = (tid & 127) >> 1 | ((tid >> 7) << 6);  // unused helper? no
    (void)rr;

    bf16x8_t kr[2], vr[2];
    #pragma unroll
    for (int p = 0; p < 2; ++p) {              // prologue: tile 0 -> regs
        const int idx = p*256 + tid;
        const int r8 = idx >> 3, cb = (idx & 7) * 8;
        kr[p] = *(const bf16x8_t*)(kp + (size_t)r8*64 + cb);
        vr[p] = *(const bf16x8_t*)(vp + (size_t)r8*1024 + cb);
    }
    #pragma unroll
    for (int p = 0; p < 2; ++p) {              // regs -> LDS
        const int idx = p*256 + tid;
        const int r8 = idx >> 3, cb = (idx & 7) * 8;
        *(bf16x8_t*)&Ks[r8*72 + cb] = kr[p];
        *(bf16x8_t*)&Vs[r8*72 + cb] = vr[p];
    }

    for (int kt = 0; kt < 16; ++kt) {
        __syncthreads();                       // staged tile visible
        if (kt < 15) {                         // issue next-tile loads (T14)
            #pragma unroll
            for (int p = 0; p < 2; ++p) {
                const int idx = p*256 + tid;
                const int r8 = idx >> 3, cb = (idx & 7) * 8;
                kr[p] = *(const bf16x8_t*)(kp + (size_t)((kt+1)*64 + r8)*64 + cb);
                vr[p] = *(const bf16x8_t*)(vp + (size_t)r8*1024 + (kt+1)*64 + cb);
            }
        }

        f32x4_t accs[4] = {};
        __builtin_amdgcn_s_setprio(1);
        #pragma unroll
        for (int c = 0; c < 4; ++c)
            #pragma unroll
            for (int ks = 0; ks < 2; ++ks) {
                bf16x8_t kf = *(const bf16x8_t*)&Ks[(c*16 + l15)*72 + ks*32 + lhi*8];
                accs[c] = __builtin_amdgcn_mfma_f32_16x16x32_bf16(qf[ks], kf, accs[c], 0, 0, 0);
            }
        __builtin_amdgcn_s_setprio(0);

        #pragma unroll
        for (int c = 0; c < 4; ++c)
            #pragma unroll
            for (int r = 0; r < 4; ++r) {
                const float pv = __expf(accs[c][r]);
                lsum[r] += pv;
                Pw[(lhi*4 + r)*72 + c*16 + l15] = f2bf(pv);
            }

        bf16x8_t pf[2];
        #pragma unroll
        for (int ks = 0; ks < 2; ++ks)
            pf[ks] = *(const bf16x8_t*)&Pw[l15*72 + ks*32 + lhi*8];
        __builtin_amdgcn_s_setprio(1);
        #pragma unroll
        for (int n = 0; n < 4; ++n)
            #pragma unroll
            for (int ks = 0; ks < 2; ++ks) {
                bf16x8_t vf = *(const bf16x8_t*)&Vs[(n*16 + l15)*72 + ks*32 + lhi*8];
                acco[n] = __builtin_amdgcn_mfma_f32_16x16x32_bf16(pf[ks], vf, acco[n], 0, 0, 0);
            }
        __builtin_amdgcn_s_setprio(0);

        __syncthreads();                       // all waves done reading Ks/Vs
        if (kt < 15) {                         // write-late into the single buffer
            #pragma unroll
            for (int p = 0; p < 2; ++p) {
                const int idx = p*256 + tid;
                const int r8 = idx >> 3, cb = (idx & 7) * 8;
                *(bf16x8_t*)&Ks[r8*72 + cb] = kr[p];
                *(bf16x8_t*)&Vs[r8*72 + cb] = vr[p];
            }
        }
    }

    #pragma unroll
    for (int r = 0; r < 4; ++r)
        #pragma unroll
        for (int off = 1; off <= 8; off <<= 1)
            lsum[r] += __shfl_xor(lsum[r], off, 64);

    const int b = bh / 12, h = bh % 12;
    #pragma unroll
    for (int n = 0; n < 4; ++n)
        #pragma unroll
        for (int r = 0; r < 4; ++r) {
            const int seq = qt*64 + w*16 + lhi*4 + r;
            obuf[((size_t)(b*1024 + seq))*768 + h*64 + n*16 + l15] = f2bf(acco[n][r] / lsum[r]);
        }
}

// ---------------- GEMM2: 64x128 tile, 4 waves (2x2), single 24KB buffer
__global__ __launch_bounds__(256, 4) void gemm_proj_bf16(
    const unsigned short* __restrict__ A, const unsigned short* __restrict__ Bt,
    const float* __restrict__ bias, float* __restrict__ out)
{
    __shared__ unsigned short As[64*64];    // 8KB
    __shared__ unsigned short Bs[128*64];   // 16KB
    const int tid = threadIdx.x;
    const int id = blockIdx.x;              // 768 blocks = 3/CU exact
    const int swz = (id & 7) * 96 + (id >> 3);
    const int n0 = (swz % 6) * 128, m0 = (swz / 6) * 64;

    const int lane = tid & 63, w = tid >> 6;
    const int l15 = lane & 15, lhi = lane >> 4;
    const int wm = w >> 1, wn = w & 1;      // 2x2 wave grid
    const int wb = tid & 192;

    const unsigned short* Ab = A  + (size_t)m0 * 768;
    const unsigned short* Bb = Bt + (size_t)n0 * 768;

    f32x4_t acc[2][4] = {};

    #pragma unroll 1
    for (int t = 0; t < 12; ++t) {
        STAGE_TILE(As, Ab, t*64, 2, 256)
        STAGE_TILE(Bs, Bb, t*64, 4, 256)
        WAIT0; BAR;
        COMPUTE_P(As, Bs)
        BAR;
    }

    #pragma unroll
    for (int n = 0; n < 4; ++n) {
        const int gcol = n0 + wn*64 + n*16 + l15;
        const float bv = bias[gcol];
        #pragma unroll
        for (int m = 0; m < 2; ++m) {
            const int grow_base = m0 + wm*32 + m*16 + lhi*4;
            #pragma unroll
            for (int reg = 0; reg < 4; ++reg)
                out[(size_t)(grow_base + reg)*768 + gcol] = acc[m][n][reg] + bv;
        }
    }
}

extern "C" void kernel_launch(void* const* d_in, const int* in_sizes, int n_in,
                              void* d_out, int out_size, void* d_ws, size_t ws_size,
                              hipStream_t stream) {
    const float* x     = (const float*)d_in[0];
    const float* Wqkv  = (const float*)d_in[1];
    const float* bqkv  = (const float*)d_in[2];
    const float* Wproj = (const float*)d_in[3];
    const float* bproj = (const float*)d_in[4];
    float* out = (float*)d_out;
    unsigned short* ws = (unsigned short*)d_ws;

    unsigned short* xb    = ws;                       // 6291456
    unsigned short* obuf  = ws;                       // alias (xb dead after gemm_qkv)
    unsigned short* wqt   = ws + 6291456u;            // 1769472
    unsigned short* wpt   = ws + 8060928u;            // 589824
    unsigned short* qb    = ws + 8650752u;            // 6291456
    unsigned short* kb    = ws + 14942208u;           // 6291456
    unsigned short* vTb   = ws + 21233664u;           // 6291456

    convert_x     <<<6144, 256, 0, stream>>>(x, xb);
    transpose_cvt <<<dim3(72, 24), 256, 0, stream>>>(Wqkv, wqt, 768, 2304);
    transpose_cvt <<<dim3(24, 24), 256, 0, stream>>>(Wproj, wpt, 768, 768);
    gemm_qkv_bf16 <<<576, 512, 0, stream>>>(xb, wqt, bqkv, qb, kb, vTb);
    attn2         <<<1536, 256, 0, stream>>>(qb, kb, vTb, obuf);
    gemm_proj_bf16<<<768, 256, 0, stream>>>(obuf, wpt, bproj, out);
}